// Round 6
// baseline (171.352 us; speedup 1.0000x reference)
//
#include <hip/hip_runtime.h>
#include <hip/hip_bf16.h>

// B=2, L=2048, D=1024, H=16, HD=64.  M = B*L = 4096, K = D = 1024.
// ws (bytes):
//   qb   @ 0MB   bf16 [32][2048][64]   (Q pre-scaled by SM_SCALE)
//   kb   @ 8MB   bf16 [32][2048][64]
//   vtb  @16MB   bf16 [32][64][2048]   (V transposed)
//   ab   @24MB   bf16 [4096][1024]     (attn concat out)
//   embb @32MB   bf16 [4096][1024]
//   wqt  @40MB   bf16 [48][64][1024]   (wqt/wkt/wvt contiguous, 2MB each)
//   wot  @46MB   bf16 [1024][1024]     (Wo transposed)

#define GM 4096
#define GK 1024
#define GL 2048
#define GH 16

typedef __attribute__((ext_vector_type(8))) short bf16x8;
typedef __attribute__((ext_vector_type(4))) float f32x4;
typedef unsigned short u16;

__device__ __forceinline__ u16 bfu(float x) {
    __hip_bfloat16 h = __float2bfloat16(x);
    return *reinterpret_cast<u16*>(&h);
}
__device__ __forceinline__ unsigned pack_bf16(float a, float b) {
    return ((unsigned)bfu(b) << 16) | bfu(a);
}
// truncation-pack two f32 -> {bf16(b), bf16(a)} in one v_perm_b32
__device__ __forceinline__ unsigned pack_trunc(float a, float b) {
    return __builtin_amdgcn_perm(__float_as_uint(b), __float_as_uint(a), 0x07060302u);
}
__device__ __forceinline__ void gl_lds16(const void* g, void* l) {
    __builtin_amdgcn_global_load_lds(
        (__attribute__((address_space(1))) void*)(g),
        (__attribute__((address_space(3))) void*)(l),
        16, 0, 0);
}
__device__ __forceinline__ float fexp2(float x) {
#if __has_builtin(__builtin_amdgcn_exp2f)
    return __builtin_amdgcn_exp2f(x);
#else
    return __expf(x * 0.6931471805599453f);
#endif
}

// 0.125 (1/sqrt(64)) folded with log2(e): softmax done in exp2 domain.
// Applied to Q in the projection epilogue, NOT in the attention kernel.
#define SM_SCALE 0.1803368801111204f
// defer-max threshold (exp2 domain): P bounded by 2^8.
#define RESCALE_THR 8.0f

// ---------------------------------------------------------------------------
// fp32 -> bf16 cast, 8 elements/thread.
// ---------------------------------------------------------------------------
__global__ __launch_bounds__(256) void cast_bf16(
    const float* __restrict__ src, u16* __restrict__ dst, int n8)
{
    int i = blockIdx.x * 256 + threadIdx.x;
    if (i >= n8) return;
    float4 v0 = reinterpret_cast<const float4*>(src)[i * 2];
    float4 v1 = reinterpret_cast<const float4*>(src)[i * 2 + 1];
    uint4 o;
    o.x = pack_bf16(v0.x, v0.y);
    o.y = pack_bf16(v0.z, v0.w);
    o.z = pack_bf16(v1.x, v1.y);
    o.w = pack_bf16(v1.z, v1.w);
    reinterpret_cast<uint4*>(dst)[i] = o;
}

// ---------------------------------------------------------------------------
// Fused Wq/Wk/Wv transpose+convert: z in [0,48) -> head (z&15) of proj (z>>4).
// ---------------------------------------------------------------------------
__global__ __launch_bounds__(256) void transpose_qkv(
    const float* __restrict__ Wq, const float* __restrict__ Wk,
    const float* __restrict__ Wv, u16* __restrict__ dst)
{
    __shared__ float T[64][65];
    const int t = threadIdx.x;
    const int z = blockIdx.z;
    const int r0 = blockIdx.x * 64;
    const float* s = (z < 16 ? Wq : (z < 32 ? Wk : Wv)) + (size_t)(z & 15) * 65536;
    u16* d = dst + (size_t)z * 65536;
#pragma unroll
    for (int i = 0; i < 4; ++i) {
        int idx = i * 256 + t;
        int row = idx >> 4, col = (idx & 15) * 4;
        float4 v = *reinterpret_cast<const float4*>(&s[(size_t)(r0 + row) * 64 + col]);
        T[row][col] = v.x; T[row][col + 1] = v.y;
        T[row][col + 2] = v.z; T[row][col + 3] = v.w;
    }
    __syncthreads();
#pragma unroll
    for (int i = 0; i < 4; ++i) {
        int idx = i * 256 + t;
        int oc = idx >> 4, ok = (idx & 15) * 4;
        ushort4 o;
        o.x = bfu(T[ok][oc]);     o.y = bfu(T[ok + 1][oc]);
        o.z = bfu(T[ok + 2][oc]); o.w = bfu(T[ok + 3][oc]);
        *reinterpret_cast<ushort4*>(&d[(size_t)oc * 1024 + r0 + ok]) = o;
    }
}

// ---------------------------------------------------------------------------
// Generic transpose+convert (for Wo): src fp32 [R][C] -> dst bf16 [C][R].
// ---------------------------------------------------------------------------
__global__ __launch_bounds__(256) void transpose_bf16(
    const float* __restrict__ src, u16* __restrict__ dst, int R, int C)
{
    __shared__ float T[64][65];
    const int t = threadIdx.x;
    const int r0 = blockIdx.x * 64, c0 = blockIdx.y * 64;
#pragma unroll
    for (int i = 0; i < 4; ++i) {
        int idx = i * 256 + t;
        int row = idx >> 4, col = (idx & 15) * 4;
        float4 v = *reinterpret_cast<const float4*>(&src[(size_t)(r0 + row) * C + c0 + col]);
        T[row][col] = v.x; T[row][col + 1] = v.y;
        T[row][col + 2] = v.z; T[row][col + 3] = v.w;
    }
    __syncthreads();
#pragma unroll
    for (int i = 0; i < 4; ++i) {
        int idx = i * 256 + t;
        int oc = idx >> 4, ok = (idx & 15) * 4;
        ushort4 o;
        o.x = bfu(T[ok][oc]);     o.y = bfu(T[ok + 1][oc]);
        o.z = bfu(T[ok + 2][oc]); o.w = bfu(T[ok + 3][oc]);
        *reinterpret_cast<ushort4*>(&dst[(size_t)(c0 + oc) * R + r0 + ok]) = o;
    }
}

// ---------------------------------------------------------------------------
// bf16 MFMA GEMM (m97 structure). fused=1: by -> proj/head; Q epilogue applies
// SM_SCALE. fused=0: by = n-tile, fp32 out.
// ---------------------------------------------------------------------------
__global__ __launch_bounds__(256) void gemm_mfma(
    const u16* __restrict__ A, const u16* __restrict__ Bt,
    float* __restrict__ Cf, u16* __restrict__ Cq, u16* __restrict__ Ck,
    u16* __restrict__ Cvt, int fused)
{
    __shared__ u16 As[128 * 64];
    __shared__ u16 Bs[64 * 64];

    const int tid  = threadIdx.x;
    const int lane = tid & 63;
    const int w    = tid >> 6;
    const int g    = lane >> 4;
    const int c15  = lane & 15;
    const int wr   = w >> 1, wc = w & 1;
    const int m0   = blockIdx.x * 128;
    const int by   = blockIdx.y;

    const u16* Bb = Bt + (size_t)by * (64 * 1024);
    const int srow8  = lane >> 3;
    const int schunk = lane & 7;

    f32x4 acc[4][2];
#pragma unroll
    for (int mf = 0; mf < 4; ++mf)
#pragma unroll
        for (int nf = 0; nf < 2; ++nf) acc[mf][nf] = f32x4{0.f, 0.f, 0.f, 0.f};

    for (int k0 = 0; k0 < GK; k0 += 64) {
#pragma unroll
        for (int c = 0; c < 4; ++c) {
            int row = c * 32 + w * 8 + srow8;
            int gc = schunk ^ (row & 7);
            gl_lds16(A + (size_t)(m0 + row) * GK + k0 + gc * 8,
                     As + c * 2048 + w * 512);
        }
#pragma unroll
        for (int c = 0; c < 2; ++c) {
            int row = c * 32 + w * 8 + srow8;
            int gc = schunk ^ (row & 7);
            gl_lds16(Bb + (size_t)row * GK + k0 + gc * 8,
                     Bs + c * 2048 + w * 512);
        }
        __syncthreads();

#pragma unroll
        for (int kc = 0; kc < 2; ++kc) {
            bf16x8 a[4], b[2];
#pragma unroll
            for (int mf = 0; mf < 4; ++mf) {
                int row = wr * 64 + mf * 16 + c15;
                int ch = (kc * 4 + g) ^ (row & 7);
                a[mf] = *reinterpret_cast<const bf16x8*>(As + row * 64 + ch * 8);
            }
#pragma unroll
            for (int nf = 0; nf < 2; ++nf) {
                int row = wc * 32 + nf * 16 + c15;
                int ch = (kc * 4 + g) ^ (row & 7);
                b[nf] = *reinterpret_cast<const bf16x8*>(Bs + row * 64 + ch * 8);
            }
#pragma unroll
            for (int mf = 0; mf < 4; ++mf)
#pragma unroll
                for (int nf = 0; nf < 2; ++nf)
                    acc[mf][nf] = __builtin_amdgcn_mfma_f32_16x16x32_bf16(
                        a[mf], b[nf], acc[mf][nf], 0, 0, 0);
        }
        __syncthreads();
    }

    // ---- epilogue ----
    if (!fused) {
#pragma unroll
        for (int mf = 0; mf < 4; ++mf) {
            int m = m0 + wr * 64 + mf * 16 + g * 4;
#pragma unroll
            for (int nf = 0; nf < 2; ++nf) {
                int n = by * 64 + wc * 32 + nf * 16 + c15;
#pragma unroll
                for (int r = 0; r < 4; ++r)
                    Cf[(size_t)(m + r) * 1024 + n] = acc[mf][nf][r];
            }
        }
        return;
    }
    const int proj = by >> 4;
    const int head = by & 15;
    const int b = m0 >> 11, l0 = m0 & 2047;
    if (proj < 2) {
        u16* C = proj ? Ck : Cq;
        const float qs = proj ? 1.f : SM_SCALE;   // pre-scale Q for softmax
        const size_t bh = ((size_t)(b * GH + head)) * GL * 64;
#pragma unroll
        for (int mf = 0; mf < 4; ++mf) {
            int l = l0 + wr * 64 + mf * 16 + g * 4;
#pragma unroll
            for (int nf = 0; nf < 2; ++nf) {
                int n = wc * 32 + nf * 16 + c15;
#pragma unroll
                for (int r = 0; r < 4; ++r)
                    C[bh + (size_t)(l + r) * 64 + n] = bfu(acc[mf][nf][r] * qs);
            }
        }
    } else {
        const size_t bh = ((size_t)(b * GH + head)) * 64 * GL;
#pragma unroll
        for (int mf = 0; mf < 4; ++mf) {
            int l = l0 + wr * 64 + mf * 16 + g * 4;
#pragma unroll
            for (int nf = 0; nf < 2; ++nf) {
                int n = wc * 32 + nf * 16 + c15;
                ushort4 o;
                o.x = bfu(acc[mf][nf][0]); o.y = bfu(acc[mf][nf][1]);
                o.z = bfu(acc[mf][nf][2]); o.w = bfu(acc[mf][nf][3]);
                *reinterpret_cast<ushort4*>(&Cvt[bh + (size_t)n * GL + l]) = o;
            }
        }
    }
}

// ---------------------------------------------------------------------------
// One KV-tile step. K from LDS (compile-time base), V^T straight from global
// (L2-resident). Defer-max online softmax (T13, THR=8 in exp2 domain).
// ---------------------------------------------------------------------------
template <bool DOMASK>
__device__ __forceinline__ void attn_step(
    const u16* __restrict__ Kt,       // LDS K tile base (compile-time offset)
    const u16* __restrict__ vbase,    // global V^T base for this bh
    uint2* Pw,
    const bf16x8* qf, int qrow, int j0, int col, int g,
    float& m_run, float& l_run, f32x4* o_acc)
{
    // ---- S^T = K . Q^T (K from swizzled LDS) ----
    f32x4 st[4];
    __builtin_amdgcn_s_setprio(1);
#pragma unroll
    for (int nt = 0; nt < 4; ++nt) {
        int row = nt * 16 + col;
        bf16x8 kf0 = *reinterpret_cast<const bf16x8*>(Kt + row * 64 + (( g      ^ (row & 7)) * 8));
        bf16x8 kf1 = *reinterpret_cast<const bf16x8*>(Kt + row * 64 + (((4 + g) ^ (row & 7)) * 8));
        f32x4 z = f32x4{0.f, 0.f, 0.f, 0.f};
        z      = __builtin_amdgcn_mfma_f32_16x16x32_bf16(kf0, qf[0], z, 0, 0, 0);
        st[nt] = __builtin_amdgcn_mfma_f32_16x16x32_bf16(kf1, qf[1], z, 0, 0, 0);
    }
    __builtin_amdgcn_s_setprio(0);

    if (DOMASK) {
#pragma unroll
        for (int nt = 0; nt < 4; ++nt)
#pragma unroll
            for (int r = 0; r < 4; ++r) {
                int kcol = j0 + nt * 16 + g * 4 + r;
                if (kcol > qrow) st[nt][r] = -__builtin_inff();
            }
    }

    // ---- tile max (tree -> v_max3 fusion) + wave reduce ----
    float mx = fmaxf(fmaxf(st[0][0], st[0][1]), fmaxf(st[0][2], st[0][3]));
    mx = fmaxf(mx, fmaxf(fmaxf(st[1][0], st[1][1]), fmaxf(st[1][2], st[1][3])));
    mx = fmaxf(mx, fmaxf(fmaxf(st[2][0], st[2][1]), fmaxf(st[2][2], st[2][3])));
    mx = fmaxf(mx, fmaxf(fmaxf(st[3][0], st[3][1]), fmaxf(st[3][2], st[3][3])));
    mx = fmaxf(mx, __shfl_xor(mx, 16));
    mx = fmaxf(mx, __shfl_xor(mx, 32));

    // ---- defer-max: rescale only when max grew past THR ----
    if (!__all(mx <= m_run + RESCALE_THR)) {
        const float mnew = fmaxf(m_run, mx);
        const float scl  = fexp2(m_run - mnew);   // first tile: exp2(-inf)=0
        l_run *= scl;
#pragma unroll
        for (int nt = 0; nt < 4; ++nt) {
            o_acc[nt][0] *= scl; o_acc[nt][1] *= scl;
            o_acc[nt][2] *= scl; o_acc[nt][3] *= scl;
        }
        m_run = mnew;
    }

    float rsum = 0.f;
    unsigned pk[4][2];
#pragma unroll
    for (int nt = 0; nt < 4; ++nt) {
        float p0 = fexp2(st[nt][0] - m_run);
        float p1 = fexp2(st[nt][1] - m_run);
        float p2 = fexp2(st[nt][2] - m_run);
        float p3 = fexp2(st[nt][3] - m_run);
        rsum += (p0 + p1) + (p2 + p3);
        pk[nt][0] = pack_trunc(p0, p1);
        pk[nt][1] = pack_trunc(p2, p3);
    }
    rsum += __shfl_xor(rsum, 16);
    rsum += __shfl_xor(rsum, 32);
    l_run += rsum;

    // ---- P -> per-wave LDS (swizzled), re-read as B-fragment of P^T ----
#pragma unroll
    for (int nt = 0; nt < 4; ++nt) {
        int unit = (((nt * 2 + (g >> 1)) ^ (col & 7)) << 1) | (g & 1);
        uint2 u; u.x = pk[nt][0]; u.y = pk[nt][1];
        Pw[col * 16 + unit] = u;
    }
    bf16x8 pf[2];
#pragma unroll
    for (int c = 0; c < 2; ++c) {
        int chunk = (c * 4 + g) ^ (col & 7);
        pf[c] = *reinterpret_cast<const bf16x8*>(&Pw[col * 16 + chunk * 2]);
    }

    // ---- O^T += V^T . P^T (V^T straight from global / L2) ----
    __builtin_amdgcn_s_setprio(1);
#pragma unroll
    for (int nt = 0; nt < 4; ++nt) {
        const u16* vb = vbase + (size_t)(nt * 16 + col) * GL + j0 + g * 8;
        bf16x8 vf0 = *reinterpret_cast<const bf16x8*>(vb);
        bf16x8 vf1 = *reinterpret_cast<const bf16x8*>(vb + 32);
        o_acc[nt] = __builtin_amdgcn_mfma_f32_16x16x32_bf16(vf0, pf[0], o_acc[nt], 0, 0, 0);
        o_acc[nt] = __builtin_amdgcn_mfma_f32_16x16x32_bf16(vf1, pf[1], o_acc[nt], 0, 0, 0);
    }
    __builtin_amdgcn_s_setprio(0);
}

// ---------------------------------------------------------------------------
// Causal flash attention, one 64-row q-tile per block (4 waves), 1024 blocks.
// Decode: slot=bid&7 (XCD), j=bid>>3; bh=slot*4+(j>>5), x=j&31. K double-
// buffered in LDS via global_load_lds (unrolled x2: compile-time buffer);
// V^T read directly from global (L2-resident). LDS = 16KB K + 8KB P = 24KB.
// ---------------------------------------------------------------------------
__global__ __launch_bounds__(256) void attn_mfma(
    const u16* __restrict__ qg, const u16* __restrict__ kg,
    const u16* __restrict__ vtg, u16* __restrict__ og)
{
    __shared__ u16 Ks[2][64 * 64];
    __shared__ uint2 Ps[4][256];

    const int tid  = threadIdx.x;
    const int lane = tid & 63;
    const int w    = tid >> 6;
    const int col  = lane & 15;
    const int g    = lane >> 4;

    const int bid  = blockIdx.x;
    const int slot = bid & 7;
    const int j    = bid >> 3;
    const int bh   = slot * 4 + (j >> 5);
    const int x    = j & 31;

    const size_t qkb  = (size_t)bh * GL * 64;
    const u16* vbase  = vtg + (size_t)bh * 64 * GL;

    const int qrow = x * 64 + w * 16 + col;
    bf16x8 qf[2];
    qf[0] = *reinterpret_cast<const bf16x8*>(qg + qkb + (size_t)qrow * 64 + g * 8);
    qf[1] = *reinterpret_cast<const bf16x8*>(qg + qkb + (size_t)qrow * 64 + 32 + g * 8);

    // K staging: wave w covers rows [w*16, w*16+16), 2 gl_lds per lane.
    const int lrow = lane >> 3;           // 0..7
    const int sch  = lane & 7;

    auto stageK = [&](int t, u16* dst) {
#pragma unroll
        for (int c = 0; c < 2; ++c) {
            const int row = w * 16 + c * 8 + lrow;
            const int gc  = sch ^ (row & 7);       // pre-swizzled source chunk
            gl_lds16(kg + qkb + (size_t)(t * 64 + row) * 64 + gc * 8,
                     dst + (w * 128 + c * 64) * 8);
        }
    };

    float m_run = -__builtin_inff(), l_run = 0.f;
    f32x4 o_acc[4];
#pragma unroll
    for (int nt = 0; nt < 4; ++nt) o_acc[nt] = f32x4{0.f, 0.f, 0.f, 0.f};

    stageK(0, Ks[0]);
    __syncthreads();

    int t = 0;
    while (t + 2 <= x) {
        stageK(t + 1, Ks[1]);
        attn_step<false>(Ks[0], vbase, Ps[w], qf, qrow, t * 64, col, g,
                         m_run, l_run, o_acc);
        __syncthreads();
        stageK(t + 2, Ks[0]);
        attn_step<false>(Ks[1], vbase, Ps[w], qf, qrow, (t + 1) * 64, col, g,
                         m_run, l_run, o_acc);
        __syncthreads();
        t += 2;
    }
    if (t < x) {   // one unmasked step left (t even -> buf0), masked uses buf1
        stageK(t + 1, Ks[1]);
        attn_step<false>(Ks[0], vbase, Ps[w], qf, qrow, t * 64, col, g,
                         m_run, l_run, o_acc);
        __syncthreads();
        attn_step<true>(Ks[1], vbase, Ps[w], qf, qrow, x * 64, col, g,
                        m_run, l_run, o_acc);
    } else {       // t == x -> masked tile already staged in buf0
        attn_step<true>(Ks[0], vbase, Ps[w], qf, qrow, x * 64, col, g,
                        m_run, l_run, o_acc);
    }

    // ---- epilogue: O[q][hd] = o_acc / l_run -> concat bf16 [B][L][H*64] ----
    const int b = bh >> 4, h = bh & 15;
    const float inv = 1.f / l_run;
#pragma unroll
    for (int nt = 0; nt < 4; ++nt) {
        ushort4 ov;
        ov.x = bfu(o_acc[nt][0] * inv);
        ov.y = bfu(o_acc[nt][1] * inv);
        ov.z = bfu(o_acc[nt][2] * inv);
        ov.w = bfu(o_acc[nt][3] * inv);
        *reinterpret_cast<ushort4*>(
            og + ((size_t)(b * GL + qrow)) * 1024 + h * 64 + nt * 16 + g * 4) = ov;
    }
}

// ---------------------------------------------------------------------------
extern "C" void kernel_launch(void* const* d_in, const int* in_sizes, int n_in,
                              void* d_out, int out_size, void* d_ws, size_t ws_size,
                              hipStream_t stream) {
    const float* emb = (const float*)d_in[0];
    const float* Wq  = (const float*)d_in[1];
    const float* Wk  = (const float*)d_in[2];
    const float* Wv  = (const float*)d_in[3];
    const float* Wo  = (const float*)d_in[4];
    float* out = (float*)d_out;

    char* ws = (char*)d_ws;
    u16* qb   = (u16*)(ws);
    u16* kb   = (u16*)(ws + ( 8u << 20));
    u16* vtb  = (u16*)(ws + (16u << 20));
    u16* ab   = (u16*)(ws + (24u << 20));
    u16* embb = (u16*)(ws + (32u << 20));
    u16* wqt  = (u16*)(ws + (40u << 20));
    u16* wot  = (u16*)(ws + (46u << 20));

    dim3 blk(256);

    cast_bf16<<<dim3(2048), blk, 0, stream>>>(emb, embb, GM * GK / 8);
    transpose_qkv<<<dim3(16, 1, 48), blk, 0, stream>>>(Wq, Wk, Wv, wqt);
    transpose_bf16<<<dim3(16, 16, 1), blk, 0, stream>>>(Wo, wot, 1024, 1024);

    // fused Q/K/V projections (one dispatch, 48 n-slices)
    gemm_mfma<<<dim3(GM / 128, 48), blk, 0, stream>>>(
        embb, wqt, nullptr, qb, kb, vtb, 1);

    // attention (1024 blocks, one q-tile each)
    attn_mfma<<<dim3(1024), blk, 0, stream>>>(qb, kb, vtb, ab);

    // output projection
    gemm_mfma<<<dim3(GM / 128, 16), blk, 0, stream>>>(
        ab, wot, out, nullptr, nullptr, nullptr, 0);
}

// Round 7
// 117.898 us; speedup vs baseline: 1.4534x; 1.4534x over previous
//
#include <hip/hip_runtime.h>
#include <hip/hip_bf16.h>

// B=2, L=2048, D=1024, H=16, HD=64.  M = B*L = 4096, K = D = 1024.
// ws (bytes):
//   qb   @ 0MB   bf16 [32][2048][64]   (Q pre-scaled by SM_SCALE)
//   kb   @ 8MB   bf16 [32][2048][64]
//   vtb  @16MB   bf16 [32][64][2048]   (V transposed)
//   ab   @24MB   bf16 [4096][1024]     (attn concat out)
//   embb @32MB   bf16 [4096][1024]
//   wqt  @40MB   bf16 [48][64][1024]   (wqt/wkt/wvt contiguous, 2MB each)
//   wot  @46MB   bf16 [1024][1024]     (Wo transposed)

#define GM 4096
#define GK 1024
#define GL 2048
#define GH 16

typedef __attribute__((ext_vector_type(8))) short bf16x8;
typedef __attribute__((ext_vector_type(4))) float f32x4;
typedef __attribute__((ext_vector_type(16))) float f32x16;
typedef unsigned short u16;

__device__ __forceinline__ u16 bfu(float x) {
    __hip_bfloat16 h = __float2bfloat16(x);
    return *reinterpret_cast<u16*>(&h);
}
__device__ __forceinline__ unsigned pack_bf16(float a, float b) {
    return ((unsigned)bfu(b) << 16) | bfu(a);
}
// truncation-pack two f32 -> {bf16(a) lo, bf16(b) hi} in one v_perm_b32
__device__ __forceinline__ unsigned pack_trunc(float a, float b) {
    return __builtin_amdgcn_perm(__float_as_uint(b), __float_as_uint(a), 0x07060302u);
}
__device__ __forceinline__ void gl_lds16(const void* g, void* l) {
    __builtin_amdgcn_global_load_lds(
        (__attribute__((address_space(1))) void*)(g),
        (__attribute__((address_space(3))) void*)(l),
        16, 0, 0);
}
__device__ __forceinline__ float fexp2(float x) {
#if __has_builtin(__builtin_amdgcn_exp2f)
    return __builtin_amdgcn_exp2f(x);
#else
    return __expf(x * 0.6931471805599453f);
#endif
}
// k-row staging permutation: tile row c holds global k-row sig5(c) (within 32).
// Makes QK^T C-regs land exactly in PV B-fragment order (own-lane, no P LDS).
__device__ __forceinline__ int sig5(int c) {
    return (c & 3) | (((c >> 3) & 1) << 2) | (((c >> 2) & 1) << 3) | (c & 16);
}

// 0.125 (1/sqrt(64)) folded with log2(e): softmax done in exp2 domain.
#define SM_SCALE 0.1803368801111204f
// defer-max threshold (exp2 domain): P bounded by 2^8.
#define RESCALE_THR 8.0f

// ---------------------------------------------------------------------------
// fp32 -> bf16 cast, 8 elements/thread.
// ---------------------------------------------------------------------------
__global__ __launch_bounds__(256) void cast_bf16(
    const float* __restrict__ src, u16* __restrict__ dst, int n8)
{
    int i = blockIdx.x * 256 + threadIdx.x;
    if (i >= n8) return;
    float4 v0 = reinterpret_cast<const float4*>(src)[i * 2];
    float4 v1 = reinterpret_cast<const float4*>(src)[i * 2 + 1];
    uint4 o;
    o.x = pack_bf16(v0.x, v0.y);
    o.y = pack_bf16(v0.z, v0.w);
    o.z = pack_bf16(v1.x, v1.y);
    o.w = pack_bf16(v1.z, v1.w);
    reinterpret_cast<uint4*>(dst)[i] = o;
}

// ---------------------------------------------------------------------------
// Fused Wq/Wk/Wv transpose+convert: z in [0,48) -> head (z&15) of proj (z>>4).
// ---------------------------------------------------------------------------
__global__ __launch_bounds__(256) void transpose_qkv(
    const float* __restrict__ Wq, const float* __restrict__ Wk,
    const float* __restrict__ Wv, u16* __restrict__ dst)
{
    __shared__ float T[64][65];
    const int t = threadIdx.x;
    const int z = blockIdx.z;
    const int r0 = blockIdx.x * 64;
    const float* s = (z < 16 ? Wq : (z < 32 ? Wk : Wv)) + (size_t)(z & 15) * 65536;
    u16* d = dst + (size_t)z * 65536;
#pragma unroll
    for (int i = 0; i < 4; ++i) {
        int idx = i * 256 + t;
        int row = idx >> 4, col = (idx & 15) * 4;
        float4 v = *reinterpret_cast<const float4*>(&s[(size_t)(r0 + row) * 64 + col]);
        T[row][col] = v.x; T[row][col + 1] = v.y;
        T[row][col + 2] = v.z; T[row][col + 3] = v.w;
    }
    __syncthreads();
#pragma unroll
    for (int i = 0; i < 4; ++i) {
        int idx = i * 256 + t;
        int oc = idx >> 4, ok = (idx & 15) * 4;
        ushort4 o;
        o.x = bfu(T[ok][oc]);     o.y = bfu(T[ok + 1][oc]);
        o.z = bfu(T[ok + 2][oc]); o.w = bfu(T[ok + 3][oc]);
        *reinterpret_cast<ushort4*>(&d[(size_t)oc * 1024 + r0 + ok]) = o;
    }
}

// ---------------------------------------------------------------------------
// Generic transpose+convert (for Wo): src fp32 [R][C] -> dst bf16 [C][R].
// ---------------------------------------------------------------------------
__global__ __launch_bounds__(256) void transpose_bf16(
    const float* __restrict__ src, u16* __restrict__ dst, int R, int C)
{
    __shared__ float T[64][65];
    const int t = threadIdx.x;
    const int r0 = blockIdx.x * 64, c0 = blockIdx.y * 64;
#pragma unroll
    for (int i = 0; i < 4; ++i) {
        int idx = i * 256 + t;
        int row = idx >> 4, col = (idx & 15) * 4;
        float4 v = *reinterpret_cast<const float4*>(&src[(size_t)(r0 + row) * C + c0 + col]);
        T[row][col] = v.x; T[row][col + 1] = v.y;
        T[row][col + 2] = v.z; T[row][col + 3] = v.w;
    }
    __syncthreads();
#pragma unroll
    for (int i = 0; i < 4; ++i) {
        int idx = i * 256 + t;
        int oc = idx >> 4, ok = (idx & 15) * 4;
        ushort4 o;
        o.x = bfu(T[ok][oc]);     o.y = bfu(T[ok + 1][oc]);
        o.z = bfu(T[ok + 2][oc]); o.w = bfu(T[ok + 3][oc]);
        *reinterpret_cast<ushort4*>(&dst[(size_t)(c0 + oc) * R + r0 + ok]) = o;
    }
}

// ---------------------------------------------------------------------------
// bf16 MFMA GEMM (m97 structure). fused=1: by -> proj/head; Q epilogue applies
// SM_SCALE. fused=0: by = n-tile, fp32 out.
// ---------------------------------------------------------------------------
__global__ __launch_bounds__(256) void gemm_mfma(
    const u16* __restrict__ A, const u16* __restrict__ Bt,
    float* __restrict__ Cf, u16* __restrict__ Cq, u16* __restrict__ Ck,
    u16* __restrict__ Cvt, int fused)
{
    __shared__ u16 As[128 * 64];
    __shared__ u16 Bs[64 * 64];

    const int tid  = threadIdx.x;
    const int lane = tid & 63;
    const int w    = tid >> 6;
    const int g    = lane >> 4;
    const int c15  = lane & 15;
    const int wr   = w >> 1, wc = w & 1;
    const int m0   = blockIdx.x * 128;
    const int by   = blockIdx.y;

    const u16* Bb = Bt + (size_t)by * (64 * 1024);
    const int srow8  = lane >> 3;
    const int schunk = lane & 7;

    f32x4 acc[4][2];
#pragma unroll
    for (int mf = 0; mf < 4; ++mf)
#pragma unroll
        for (int nf = 0; nf < 2; ++nf) acc[mf][nf] = f32x4{0.f, 0.f, 0.f, 0.f};

    for (int k0 = 0; k0 < GK; k0 += 64) {
#pragma unroll
        for (int c = 0; c < 4; ++c) {
            int row = c * 32 + w * 8 + srow8;
            int gc = schunk ^ (row & 7);
            gl_lds16(A + (size_t)(m0 + row) * GK + k0 + gc * 8,
                     As + c * 2048 + w * 512);
        }
#pragma unroll
        for (int c = 0; c < 2; ++c) {
            int row = c * 32 + w * 8 + srow8;
            int gc = schunk ^ (row & 7);
            gl_lds16(Bb + (size_t)row * GK + k0 + gc * 8,
                     Bs + c * 2048 + w * 512);
        }
        __syncthreads();

#pragma unroll
        for (int kc = 0; kc < 2; ++kc) {
            bf16x8 a[4], b[2];
#pragma unroll
            for (int mf = 0; mf < 4; ++mf) {
                int row = wr * 64 + mf * 16 + c15;
                int ch = (kc * 4 + g) ^ (row & 7);
                a[mf] = *reinterpret_cast<const bf16x8*>(As + row * 64 + ch * 8);
            }
#pragma unroll
            for (int nf = 0; nf < 2; ++nf) {
                int row = wc * 32 + nf * 16 + c15;
                int ch = (kc * 4 + g) ^ (row & 7);
                b[nf] = *reinterpret_cast<const bf16x8*>(Bs + row * 64 + ch * 8);
            }
#pragma unroll
            for (int mf = 0; mf < 4; ++mf)
#pragma unroll
                for (int nf = 0; nf < 2; ++nf)
                    acc[mf][nf] = __builtin_amdgcn_mfma_f32_16x16x32_bf16(
                        a[mf], b[nf], acc[mf][nf], 0, 0, 0);
        }
        __syncthreads();
    }

    // ---- epilogue ----
    if (!fused) {
#pragma unroll
        for (int mf = 0; mf < 4; ++mf) {
            int m = m0 + wr * 64 + mf * 16 + g * 4;
#pragma unroll
            for (int nf = 0; nf < 2; ++nf) {
                int n = by * 64 + wc * 32 + nf * 16 + c15;
#pragma unroll
                for (int r = 0; r < 4; ++r)
                    Cf[(size_t)(m + r) * 1024 + n] = acc[mf][nf][r];
            }
        }
        return;
    }
    const int proj = by >> 4;
    const int head = by & 15;
    const int b = m0 >> 11, l0 = m0 & 2047;
    if (proj < 2) {
        u16* C = proj ? Ck : Cq;
        const float qs = proj ? 1.f : SM_SCALE;   // pre-scale Q for softmax
        const size_t bh = ((size_t)(b * GH + head)) * GL * 64;
#pragma unroll
        for (int mf = 0; mf < 4; ++mf) {
            int l = l0 + wr * 64 + mf * 16 + g * 4;
#pragma unroll
            for (int nf = 0; nf < 2; ++nf) {
                int n = wc * 32 + nf * 16 + c15;
#pragma unroll
                for (int r = 0; r < 4; ++r)
                    C[bh + (size_t)(l + r) * 64 + n] = bfu(acc[mf][nf][r] * qs);
            }
        }
    } else {
        const size_t bh = ((size_t)(b * GH + head)) * 64 * GL;
#pragma unroll
        for (int mf = 0; mf < 4; ++mf) {
            int l = l0 + wr * 64 + mf * 16 + g * 4;
#pragma unroll
            for (int nf = 0; nf < 2; ++nf) {
                int n = wc * 32 + nf * 16 + c15;
                ushort4 o;
                o.x = bfu(acc[mf][nf][0]); o.y = bfu(acc[mf][nf][1]);
                o.z = bfu(acc[mf][nf][2]); o.w = bfu(acc[mf][nf][3]);
                *reinterpret_cast<ushort4*>(&Cvt[bh + (size_t)n * GL + l]) = o;
            }
        }
    }
}

// ---------------------------------------------------------------------------
// One 64-k KV step, 32x32x16 MFMA, 32 q-rows per wave (swapped operands).
// K tile is sigma-permuted at staging so QK^T C-regs == PV B-frag order:
// P stays entirely in registers (no LDS round-trip, no cross-lane moves).
// ---------------------------------------------------------------------------
template <bool DOMASK>
__device__ __forceinline__ void attn_step32(
    const u16* __restrict__ Kt, const u16* __restrict__ Vt,
    const bf16x8* qf, int qrow, int j0, int qi, int hi,
    float& m_run, float& l_run, f32x16& o0, f32x16& o1)
{
    const int swz = qi & 7;   // rows qi and 32+qi share (row&7)

    // ---- S^T = K . Q^T : two stacked 32x32 tiles, d-contraction = 4 MFMA ----
    f32x16 s0 = {0.f,0.f,0.f,0.f,0.f,0.f,0.f,0.f,0.f,0.f,0.f,0.f,0.f,0.f,0.f,0.f};
    f32x16 s1 = s0;
#pragma unroll
    for (int dc = 0; dc < 4; ++dc) {
        const int ch = ((dc * 2 + hi) ^ swz) * 8;
        bf16x8 kf0 = *reinterpret_cast<const bf16x8*>(Kt + qi * 64 + ch);
        bf16x8 kf1 = *reinterpret_cast<const bf16x8*>(Kt + (32 + qi) * 64 + ch);
        s0 = __builtin_amdgcn_mfma_f32_32x32x16_bf16(kf0, qf[dc], s0, 0, 0, 0);
        s1 = __builtin_amdgcn_mfma_f32_32x32x16_bf16(kf1, qf[dc], s1, 0, 0, 0);
    }

    // reg r of tile kt holds S for global k = j0 + 32*kt + klocal(r,hi):
    // klocal = (r&3) + 4*((r>>2)&1) + 8*hi + 16*((r>>3)&1)   [sigma mapping]
    if (DOMASK) {
#pragma unroll
        for (int r = 0; r < 16; ++r) {
            const int kl = (r & 3) + (((r >> 2) & 1) << 2) + (hi << 3)
                         + (((r >> 3) & 1) << 4);
            if (j0 + kl > qrow)      s0[r] = -__builtin_inff();
            if (j0 + 32 + kl > qrow) s1[r] = -__builtin_inff();
        }
    }

    // ---- row max: 4 chains then combine; cross-lane only xor-32 ----
    float ma = fmaxf(s0[0], s0[1]), mb = fmaxf(s0[2], s0[3]);
    float mc = fmaxf(s1[0], s1[1]), md = fmaxf(s1[2], s1[3]);
#pragma unroll
    for (int r = 4; r < 16; r += 4) {
        ma = fmaxf(ma, fmaxf(s0[r], s0[r + 1]));
        mb = fmaxf(mb, fmaxf(s0[r + 2], s0[r + 3]));
        mc = fmaxf(mc, fmaxf(s1[r], s1[r + 1]));
        md = fmaxf(md, fmaxf(s1[r + 2], s1[r + 3]));
    }
    float mx = fmaxf(fmaxf(ma, mb), fmaxf(mc, md));
    mx = fmaxf(mx, __shfl_xor(mx, 32));

    // ---- defer-max rescale (T13) ----
    if (!__all(mx <= m_run + RESCALE_THR)) {
        const float mnew = fmaxf(m_run, mx);
        const float scl  = fexp2(m_run - mnew);   // first tile: exp2(-inf)=0
        l_run *= scl;
        o0 *= scl;
        o1 *= scl;
        m_run = mnew;
    }

    // ---- exp + pack (pair p packs regs 2p,2p+1 = consecutive k) ----
    float rsum = 0.f;
    unsigned pk0[8], pk1[8];
#pragma unroll
    for (int p = 0; p < 8; ++p) {
        float a = fexp2(s0[2 * p] - m_run), b = fexp2(s0[2 * p + 1] - m_run);
        float c = fexp2(s1[2 * p] - m_run), d = fexp2(s1[2 * p + 1] - m_run);
        rsum += (a + b) + (c + d);
        pk0[p] = pack_trunc(a, b);
        pk1[p] = pack_trunc(c, d);
    }
    rsum += __shfl_xor(rsum, 32);
    l_run += rsum;

    // ---- O^T += V^T . P^T : B-frag j = packed pairs [4*(j&1)..+3] of tile j>>1
    __builtin_amdgcn_s_setprio(1);
#pragma unroll
    for (int j2 = 0; j2 < 4; ++j2) {
        const int J4 = (j2 & 1) * 4;
        uint4 uu;
        if (j2 < 2) { uu.x = pk0[J4]; uu.y = pk0[J4 + 1]; uu.z = pk0[J4 + 2]; uu.w = pk0[J4 + 3]; }
        else        { uu.x = pk1[J4]; uu.y = pk1[J4 + 1]; uu.z = pk1[J4 + 2]; uu.w = pk1[J4 + 3]; }
        bf16x8 pf = __builtin_bit_cast(bf16x8, uu);
        const int chv = ((j2 * 2 + hi) ^ swz) * 8;
        bf16x8 vf0 = *reinterpret_cast<const bf16x8*>(Vt + qi * 64 + chv);
        bf16x8 vf1 = *reinterpret_cast<const bf16x8*>(Vt + (32 + qi) * 64 + chv);
        o0 = __builtin_amdgcn_mfma_f32_32x32x16_bf16(vf0, pf, o0, 0, 0, 0);
        o1 = __builtin_amdgcn_mfma_f32_32x32x16_bf16(vf1, pf, o1, 0, 0, 0);
    }
    __builtin_amdgcn_s_setprio(0);
}

// ---------------------------------------------------------------------------
// Causal flash attention: 1024 blocks x 128 threads (2 waves, 32 q-rows each).
// Decode: slot=bid&7 (XCD), j=bid>>3, sub=j>>5; bh=slot*4+sub,
// x=(j+13*sub)&31 (mixes long/short blocks on co-resident slots).
// K/V double-buffered in LDS (32KB) via global_load_lds; K rows sigma-permuted.
// ---------------------------------------------------------------------------
__global__ __launch_bounds__(128) void attn_mfma(
    const u16* __restrict__ qg, const u16* __restrict__ kg,
    const u16* __restrict__ vtg, u16* __restrict__ og)
{
    __shared__ u16 Ks[2][64 * 64];
    __shared__ u16 Vs[2][64 * 64];

    const int tid  = threadIdx.x;
    const int lane = tid & 63;
    const int w    = tid >> 6;     // wave 0/1
    const int qi   = lane & 31;
    const int hi   = lane >> 5;

    const int bid  = blockIdx.x;
    const int slot = bid & 7;
    const int j    = bid >> 3;
    const int sub  = j >> 5;
    const int bh   = slot * 4 + sub;
    const int x    = (j + 13 * sub) & 31;

    const size_t qkb  = (size_t)bh * GL * 64;
    const size_t vtbo = (size_t)bh * 64 * GL;

    const int qrow = x * 64 + w * 32 + qi;
    bf16x8 qf[4];
#pragma unroll
    for (int dc = 0; dc < 4; ++dc)
        qf[dc] = *reinterpret_cast<const bf16x8*>(
            qg + qkb + (size_t)qrow * 64 + dc * 16 + hi * 8);

    const int lrow = lane >> 3;    // 0..7
    const int lch  = lane & 7;

    auto stage = [&](int t, u16* kd, u16* vd) {
#pragma unroll
        for (int c = 0; c < 4; ++c) {
            const int row = c * 16 + w * 8 + lrow;       // tile row 0..63
            const int gc  = lch ^ (row & 7);             // pre-swizzled chunk
            const int ksrc = t * 64 + (row & 32) + sig5(row & 31);
            gl_lds16(kg + qkb + (size_t)ksrc * 64 + gc * 8,
                     kd + (c * 128 + w * 64) * 8);
            gl_lds16(vtg + vtbo + (size_t)row * GL + t * 64 + gc * 8,
                     vd + (c * 128 + w * 64) * 8);
        }
    };

    float m_run = -__builtin_inff(), l_run = 0.f;
    f32x16 o0 = {0.f,0.f,0.f,0.f,0.f,0.f,0.f,0.f,0.f,0.f,0.f,0.f,0.f,0.f,0.f,0.f};
    f32x16 o1 = o0;

    stage(0, Ks[0], Vs[0]);
    __syncthreads();

    int t = 0;
    while (t + 2 <= x) {
        stage(t + 1, Ks[1], Vs[1]);
        attn_step32<false>(Ks[0], Vs[0], qf, qrow, t * 64, qi, hi, m_run, l_run, o0, o1);
        __syncthreads();
        stage(t + 2, Ks[0], Vs[0]);
        attn_step32<false>(Ks[1], Vs[1], qf, qrow, (t + 1) * 64, qi, hi, m_run, l_run, o0, o1);
        __syncthreads();
        t += 2;
    }
    if (t < x) {   // t == x-1: one unmasked step from buf0, masked from buf1
        stage(x, Ks[1], Vs[1]);
        attn_step32<false>(Ks[0], Vs[0], qf, qrow, t * 64, qi, hi, m_run, l_run, o0, o1);
        __syncthreads();
        attn_step32<true>(Ks[1], Vs[1], qf, qrow, x * 64, qi, hi, m_run, l_run, o0, o1);
    } else {       // t == x: masked tile already in buf0
        attn_step32<true>(Ks[0], Vs[0], qf, qrow, x * 64, qi, hi, m_run, l_run, o0, o1);
    }

    // ---- epilogue: O[q][hd], hd = (r&3) + 8*(r>>2) + 4*hi (+32 for o1) ----
    const int b = bh >> 4, h = bh & 15;
    const float inv = 1.f / l_run;
    u16* obase = og + ((size_t)(b * GL + qrow)) * 1024 + h * 64 + 4 * hi;
#pragma unroll
    for (int rq = 0; rq < 4; ++rq) {
        ushort4 w0, w1;
        w0.x = bfu(o0[4 * rq] * inv);     w0.y = bfu(o0[4 * rq + 1] * inv);
        w0.z = bfu(o0[4 * rq + 2] * inv); w0.w = bfu(o0[4 * rq + 3] * inv);
        *reinterpret_cast<ushort4*>(obase + 8 * rq) = w0;
        w1.x = bfu(o1[4 * rq] * inv);     w1.y = bfu(o1[4 * rq + 1] * inv);
        w1.z = bfu(o1[4 * rq + 2] * inv); w1.w = bfu(o1[4 * rq + 3] * inv);
        *reinterpret_cast<ushort4*>(obase + 32 + 8 * rq) = w1;
    }
}

// ---------------------------------------------------------------------------
extern "C" void kernel_launch(void* const* d_in, const int* in_sizes, int n_in,
                              void* d_out, int out_size, void* d_ws, size_t ws_size,
                              hipStream_t stream) {
    const float* emb = (const float*)d_in[0];
    const float* Wq  = (const float*)d_in[1];
    const float* Wk  = (const float*)d_in[2];
    const float* Wv  = (const float*)d_in[3];
    const float* Wo  = (const float*)d_in[4];
    float* out = (float*)d_out;

    char* ws = (char*)d_ws;
    u16* qb   = (u16*)(ws);
    u16* kb   = (u16*)(ws + ( 8u << 20));
    u16* vtb  = (u16*)(ws + (16u << 20));
    u16* ab   = (u16*)(ws + (24u << 20));
    u16* embb = (u16*)(ws + (32u << 20));
    u16* wqt  = (u16*)(ws + (40u << 20));
    u16* wot  = (u16*)(ws + (46u << 20));

    dim3 blk(256);

    cast_bf16<<<dim3(2048), blk, 0, stream>>>(emb, embb, GM * GK / 8);
    transpose_qkv<<<dim3(16, 1, 48), blk, 0, stream>>>(Wq, Wk, Wv, wqt);
    transpose_bf16<<<dim3(16, 16, 1), blk, 0, stream>>>(Wo, wot, 1024, 1024);

    // fused Q/K/V projections (one dispatch, 48 n-slices)
    gemm_mfma<<<dim3(GM / 128, 48), blk, 0, stream>>>(
        embb, wqt, nullptr, qb, kb, vtb, 1);

    // attention: 1024 blocks x 2 waves, 32x32 MFMA, in-register P
    attn_mfma<<<dim3(1024), dim3(128), 0, stream>>>(qb, kb, vtb, ab);

    // output projection
    gemm_mfma<<<dim3(GM / 128, 16), blk, 0, stream>>>(
        ab, wot, out, nullptr, nullptr, nullptr, 0);
}

// Round 8
// 109.883 us; speedup vs baseline: 1.5594x; 1.0729x over previous
//
#include <hip/hip_runtime.h>
#include <hip/hip_bf16.h>

// B=2, L=2048, D=1024, H=16, HD=64.  M = B*L = 4096, K = D = 1024.
// ws (bytes):
//   qb   @ 0MB   bf16 [32][2048][64]   (Q pre-scaled by SM_SCALE)
//   kb   @ 8MB   bf16 [32][2048][64]
//   vtb  @16MB   bf16 [32][64][2048]   (V transposed)
//   ab   @24MB   bf16 [4096][1024]     (attn concat out)
//   embb @32MB   bf16 [4096][1024]
//   wqt  @40MB   bf16 [48][64][1024]   (wqt/wkt/wvt contiguous, 2MB each)
//   wot  @46MB   bf16 [1024][1024]     (Wo transposed)

#define GM 4096
#define GK 1024
#define GL 2048
#define GH 16

typedef __attribute__((ext_vector_type(8))) short bf16x8;
typedef __attribute__((ext_vector_type(4))) float f32x4;
typedef __attribute__((ext_vector_type(16))) float f32x16;
typedef unsigned short u16;

__device__ __forceinline__ u16 bfu(float x) {
    __hip_bfloat16 h = __float2bfloat16(x);
    return *reinterpret_cast<u16*>(&h);
}
__device__ __forceinline__ unsigned pack_bf16(float a, float b) {
    return ((unsigned)bfu(b) << 16) | bfu(a);
}
// truncation-pack two f32 -> {bf16(a) lo, bf16(b) hi} in one v_perm_b32
__device__ __forceinline__ unsigned pack_trunc(float a, float b) {
    return __builtin_amdgcn_perm(__float_as_uint(b), __float_as_uint(a), 0x07060302u);
}
__device__ __forceinline__ void gl_lds16(const void* g, void* l) {
    __builtin_amdgcn_global_load_lds(
        (__attribute__((address_space(1))) void*)(g),
        (__attribute__((address_space(3))) void*)(l),
        16, 0, 0);
}
__device__ __forceinline__ float fexp2(float x) {
#if __has_builtin(__builtin_amdgcn_exp2f)
    return __builtin_amdgcn_exp2f(x);
#else
    return __expf(x * 0.6931471805599453f);
#endif
}
// k-row staging permutation: tile row c holds global k-row sig5(c) (within 32).
// Makes QK^T C-regs land exactly in PV B-fragment order (own-lane, no P LDS).
__device__ __forceinline__ int sig5(int c) {
    return (c & 3) | (((c >> 3) & 1) << 2) | (((c >> 2) & 1) << 3) | (c & 16);
}

// 0.125 (1/sqrt(64)) folded with log2(e): softmax done in exp2 domain.
#define SM_SCALE 0.1803368801111204f
// defer-max threshold (exp2 domain): P bounded by 2^8.
#define RESCALE_THR 8.0f

// ---------------------------------------------------------------------------
// fp32 -> bf16 cast, 8 elements/thread.
// ---------------------------------------------------------------------------
__global__ __launch_bounds__(256) void cast_bf16(
    const float* __restrict__ src, u16* __restrict__ dst, int n8)
{
    int i = blockIdx.x * 256 + threadIdx.x;
    if (i >= n8) return;
    float4 v0 = reinterpret_cast<const float4*>(src)[i * 2];
    float4 v1 = reinterpret_cast<const float4*>(src)[i * 2 + 1];
    uint4 o;
    o.x = pack_bf16(v0.x, v0.y);
    o.y = pack_bf16(v0.z, v0.w);
    o.z = pack_bf16(v1.x, v1.y);
    o.w = pack_bf16(v1.z, v1.w);
    reinterpret_cast<uint4*>(dst)[i] = o;
}

// ---------------------------------------------------------------------------
// Fused Wq/Wk/Wv transpose+convert: z in [0,48) -> head (z&15) of proj (z>>4).
// ---------------------------------------------------------------------------
__global__ __launch_bounds__(256) void transpose_qkv(
    const float* __restrict__ Wq, const float* __restrict__ Wk,
    const float* __restrict__ Wv, u16* __restrict__ dst)
{
    __shared__ float T[64][65];
    const int t = threadIdx.x;
    const int z = blockIdx.z;
    const int r0 = blockIdx.x * 64;
    const float* s = (z < 16 ? Wq : (z < 32 ? Wk : Wv)) + (size_t)(z & 15) * 65536;
    u16* d = dst + (size_t)z * 65536;
#pragma unroll
    for (int i = 0; i < 4; ++i) {
        int idx = i * 256 + t;
        int row = idx >> 4, col = (idx & 15) * 4;
        float4 v = *reinterpret_cast<const float4*>(&s[(size_t)(r0 + row) * 64 + col]);
        T[row][col] = v.x; T[row][col + 1] = v.y;
        T[row][col + 2] = v.z; T[row][col + 3] = v.w;
    }
    __syncthreads();
#pragma unroll
    for (int i = 0; i < 4; ++i) {
        int idx = i * 256 + t;
        int oc = idx >> 4, ok = (idx & 15) * 4;
        ushort4 o;
        o.x = bfu(T[ok][oc]);     o.y = bfu(T[ok + 1][oc]);
        o.z = bfu(T[ok + 2][oc]); o.w = bfu(T[ok + 3][oc]);
        *reinterpret_cast<ushort4*>(&d[(size_t)oc * 1024 + r0 + ok]) = o;
    }
}

// ---------------------------------------------------------------------------
// Generic transpose+convert (for Wo): src fp32 [R][C] -> dst bf16 [C][R].
// ---------------------------------------------------------------------------
__global__ __launch_bounds__(256) void transpose_bf16(
    const float* __restrict__ src, u16* __restrict__ dst, int R, int C)
{
    __shared__ float T[64][65];
    const int t = threadIdx.x;
    const int r0 = blockIdx.x * 64, c0 = blockIdx.y * 64;
#pragma unroll
    for (int i = 0; i < 4; ++i) {
        int idx = i * 256 + t;
        int row = idx >> 4, col = (idx & 15) * 4;
        float4 v = *reinterpret_cast<const float4*>(&src[(size_t)(r0 + row) * C + c0 + col]);
        T[row][col] = v.x; T[row][col + 1] = v.y;
        T[row][col + 2] = v.z; T[row][col + 3] = v.w;
    }
    __syncthreads();
#pragma unroll
    for (int i = 0; i < 4; ++i) {
        int idx = i * 256 + t;
        int oc = idx >> 4, ok = (idx & 15) * 4;
        ushort4 o;
        o.x = bfu(T[ok][oc]);     o.y = bfu(T[ok + 1][oc]);
        o.z = bfu(T[ok + 2][oc]); o.w = bfu(T[ok + 3][oc]);
        *reinterpret_cast<ushort4*>(&dst[(size_t)(c0 + oc) * R + r0 + ok]) = o;
    }
}

// ---------------------------------------------------------------------------
// bf16 MFMA GEMM (m97 structure). fused=1: by -> proj/head; Q epilogue applies
// SM_SCALE. fused=0: by = n-tile, fp32 out.
// ---------------------------------------------------------------------------
__global__ __launch_bounds__(256) void gemm_mfma(
    const u16* __restrict__ A, const u16* __restrict__ Bt,
    float* __restrict__ Cf, u16* __restrict__ Cq, u16* __restrict__ Ck,
    u16* __restrict__ Cvt, int fused)
{
    __shared__ u16 As[128 * 64];
    __shared__ u16 Bs[64 * 64];

    const int tid  = threadIdx.x;
    const int lane = tid & 63;
    const int w    = tid >> 6;
    const int g    = lane >> 4;
    const int c15  = lane & 15;
    const int wr   = w >> 1, wc = w & 1;
    const int m0   = blockIdx.x * 128;
    const int by   = blockIdx.y;

    const u16* Bb = Bt + (size_t)by * (64 * 1024);
    const int srow8  = lane >> 3;
    const int schunk = lane & 7;

    f32x4 acc[4][2];
#pragma unroll
    for (int mf = 0; mf < 4; ++mf)
#pragma unroll
        for (int nf = 0; nf < 2; ++nf) acc[mf][nf] = f32x4{0.f, 0.f, 0.f, 0.f};

    for (int k0 = 0; k0 < GK; k0 += 64) {
#pragma unroll
        for (int c = 0; c < 4; ++c) {
            int row = c * 32 + w * 8 + srow8;
            int gc = schunk ^ (row & 7);
            gl_lds16(A + (size_t)(m0 + row) * GK + k0 + gc * 8,
                     As + c * 2048 + w * 512);
        }
#pragma unroll
        for (int c = 0; c < 2; ++c) {
            int row = c * 32 + w * 8 + srow8;
            int gc = schunk ^ (row & 7);
            gl_lds16(Bb + (size_t)row * GK + k0 + gc * 8,
                     Bs + c * 2048 + w * 512);
        }
        __syncthreads();

#pragma unroll
        for (int kc = 0; kc < 2; ++kc) {
            bf16x8 a[4], b[2];
#pragma unroll
            for (int mf = 0; mf < 4; ++mf) {
                int row = wr * 64 + mf * 16 + c15;
                int ch = (kc * 4 + g) ^ (row & 7);
                a[mf] = *reinterpret_cast<const bf16x8*>(As + row * 64 + ch * 8);
            }
#pragma unroll
            for (int nf = 0; nf < 2; ++nf) {
                int row = wc * 32 + nf * 16 + c15;
                int ch = (kc * 4 + g) ^ (row & 7);
                b[nf] = *reinterpret_cast<const bf16x8*>(Bs + row * 64 + ch * 8);
            }
#pragma unroll
            for (int mf = 0; mf < 4; ++mf)
#pragma unroll
                for (int nf = 0; nf < 2; ++nf)
                    acc[mf][nf] = __builtin_amdgcn_mfma_f32_16x16x32_bf16(
                        a[mf], b[nf], acc[mf][nf], 0, 0, 0);
        }
        __syncthreads();
    }

    // ---- epilogue ----
    if (!fused) {
#pragma unroll
        for (int mf = 0; mf < 4; ++mf) {
            int m = m0 + wr * 64 + mf * 16 + g * 4;
#pragma unroll
            for (int nf = 0; nf < 2; ++nf) {
                int n = by * 64 + wc * 32 + nf * 16 + c15;
#pragma unroll
                for (int r = 0; r < 4; ++r)
                    Cf[(size_t)(m + r) * 1024 + n] = acc[mf][nf][r];
            }
        }
        return;
    }
    const int proj = by >> 4;
    const int head = by & 15;
    const int b = m0 >> 11, l0 = m0 & 2047;
    if (proj < 2) {
        u16* C = proj ? Ck : Cq;
        const float qs = proj ? 1.f : SM_SCALE;   // pre-scale Q for softmax
        const size_t bh = ((size_t)(b * GH + head)) * GL * 64;
#pragma unroll
        for (int mf = 0; mf < 4; ++mf) {
            int l = l0 + wr * 64 + mf * 16 + g * 4;
#pragma unroll
            for (int nf = 0; nf < 2; ++nf) {
                int n = wc * 32 + nf * 16 + c15;
#pragma unroll
                for (int r = 0; r < 4; ++r)
                    C[bh + (size_t)(l + r) * 64 + n] = bfu(acc[mf][nf][r] * qs);
            }
        }
    } else {
        const size_t bh = ((size_t)(b * GH + head)) * 64 * GL;
#pragma unroll
        for (int mf = 0; mf < 4; ++mf) {
            int l = l0 + wr * 64 + mf * 16 + g * 4;
#pragma unroll
            for (int nf = 0; nf < 2; ++nf) {
                int n = wc * 32 + nf * 16 + c15;
                ushort4 o;
                o.x = bfu(acc[mf][nf][0]); o.y = bfu(acc[mf][nf][1]);
                o.z = bfu(acc[mf][nf][2]); o.w = bfu(acc[mf][nf][3]);
                *reinterpret_cast<ushort4*>(&Cvt[bh + (size_t)n * GL + l]) = o;
            }
        }
    }
}

// ---------------------------------------------------------------------------
// One 64-k KV step, 32x32x16 MFMA, 32 q-rows per wave (swapped operands).
// K tile is sigma-permuted at staging so QK^T C-regs == PV B-frag order:
// P stays entirely in registers (no LDS round-trip, no cross-lane moves).
// ---------------------------------------------------------------------------
template <bool DOMASK>
__device__ __forceinline__ void attn_step32(
    const u16* __restrict__ Kt, const u16* __restrict__ Vt,
    const bf16x8* qf, int qrow, int j0, int qi, int hi,
    float& m_run, float& l_run, f32x16& o0, f32x16& o1)
{
    const int swz = qi & 7;   // rows qi and 32+qi share (row&7)

    // ---- S^T = K . Q^T : two stacked 32x32 tiles, d-contraction = 4 MFMA ----
    f32x16 s0 = {0.f,0.f,0.f,0.f,0.f,0.f,0.f,0.f,0.f,0.f,0.f,0.f,0.f,0.f,0.f,0.f};
    f32x16 s1 = s0;
#pragma unroll
    for (int dc = 0; dc < 4; ++dc) {
        const int ch = ((dc * 2 + hi) ^ swz) * 8;
        bf16x8 kf0 = *reinterpret_cast<const bf16x8*>(Kt + qi * 64 + ch);
        bf16x8 kf1 = *reinterpret_cast<const bf16x8*>(Kt + (32 + qi) * 64 + ch);
        s0 = __builtin_amdgcn_mfma_f32_32x32x16_bf16(kf0, qf[dc], s0, 0, 0, 0);
        s1 = __builtin_amdgcn_mfma_f32_32x32x16_bf16(kf1, qf[dc], s1, 0, 0, 0);
    }

    // reg r of tile kt holds S for global k = j0 + 32*kt + klocal(r,hi):
    // klocal = (r&3) + 4*((r>>2)&1) + 8*hi + 16*((r>>3)&1)   [sigma mapping]
    if (DOMASK) {
#pragma unroll
        for (int r = 0; r < 16; ++r) {
            const int kl = (r & 3) + (((r >> 2) & 1) << 2) + (hi << 3)
                         + (((r >> 3) & 1) << 4);
            if (j0 + kl > qrow)      s0[r] = -__builtin_inff();
            if (j0 + 32 + kl > qrow) s1[r] = -__builtin_inff();
        }
    }

    // ---- row max: 4 chains then combine; cross-lane only xor-32 ----
    float ma = fmaxf(s0[0], s0[1]), mb = fmaxf(s0[2], s0[3]);
    float mc = fmaxf(s1[0], s1[1]), md = fmaxf(s1[2], s1[3]);
#pragma unroll
    for (int r = 4; r < 16; r += 4) {
        ma = fmaxf(ma, fmaxf(s0[r], s0[r + 1]));
        mb = fmaxf(mb, fmaxf(s0[r + 2], s0[r + 3]));
        mc = fmaxf(mc, fmaxf(s1[r], s1[r + 1]));
        md = fmaxf(md, fmaxf(s1[r + 2], s1[r + 3]));
    }
    float mx = fmaxf(fmaxf(ma, mb), fmaxf(mc, md));
    mx = fmaxf(mx, __shfl_xor(mx, 32));

    // ---- defer-max rescale (T13) ----
    if (!__all(mx <= m_run + RESCALE_THR)) {
        const float mnew = fmaxf(m_run, mx);
        const float scl  = fexp2(m_run - mnew);   // first tile: exp2(-inf)=0
        l_run *= scl;
        o0 *= scl;
        o1 *= scl;
        m_run = mnew;
    }

    // ---- exp + pack (pair p packs regs 2p,2p+1 = consecutive k) ----
    float rsum = 0.f;
    unsigned pk0[8], pk1[8];
#pragma unroll
    for (int p = 0; p < 8; ++p) {
        float a = fexp2(s0[2 * p] - m_run), b = fexp2(s0[2 * p + 1] - m_run);
        float c = fexp2(s1[2 * p] - m_run), d = fexp2(s1[2 * p + 1] - m_run);
        rsum += (a + b) + (c + d);
        pk0[p] = pack_trunc(a, b);
        pk1[p] = pack_trunc(c, d);
    }
    rsum += __shfl_xor(rsum, 32);
    l_run += rsum;

    // ---- O^T += V^T . P^T : B-frag j = packed pairs [4*(j&1)..+3] of tile j>>1
    __builtin_amdgcn_s_setprio(1);
#pragma unroll
    for (int j2 = 0; j2 < 4; ++j2) {
        const int J4 = (j2 & 1) * 4;
        uint4 uu;
        if (j2 < 2) { uu.x = pk0[J4]; uu.y = pk0[J4 + 1]; uu.z = pk0[J4 + 2]; uu.w = pk0[J4 + 3]; }
        else        { uu.x = pk1[J4]; uu.y = pk1[J4 + 1]; uu.z = pk1[J4 + 2]; uu.w = pk1[J4 + 3]; }
        bf16x8 pf = __builtin_bit_cast(bf16x8, uu);
        const int chv = ((j2 * 2 + hi) ^ swz) * 8;
        bf16x8 vf0 = *reinterpret_cast<const bf16x8*>(Vt + qi * 64 + chv);
        bf16x8 vf1 = *reinterpret_cast<const bf16x8*>(Vt + (32 + qi) * 64 + chv);
        o0 = __builtin_amdgcn_mfma_f32_32x32x16_bf16(vf0, pf, o0, 0, 0, 0);
        o1 = __builtin_amdgcn_mfma_f32_32x32x16_bf16(vf1, pf, o1, 0, 0, 0);
    }
    __builtin_amdgcn_s_setprio(0);
}

// ---------------------------------------------------------------------------
// Causal flash attention: 512 blocks x 256 threads (4 waves x 32 q-rows =
// 128-row chunk). Decode: j=bid&255, half=bid>>8; bh=j&31 (XCD=bh%8, 4
// heads/XCD), s=j>>5, chunk c = half? 15-s : s. Under the standard bid->CU
// round-robin, bid and bid+256 share a CU: steps (2s+2)+(2(15-s)+2)=36
// uniform per CU. K/V staged once per 128 q-rows (half the stage traffic of
// the 64-row version); 2 blocks/CU -> 8 waves/CU = 2/SIMD.
// Tail: tile 2c masked for waves 0-1 only; tile 2c+1 only for waves 2-3.
// ---------------------------------------------------------------------------
__global__ __launch_bounds__(256) void attn_mfma(
    const u16* __restrict__ qg, const u16* __restrict__ kg,
    const u16* __restrict__ vtg, u16* __restrict__ og)
{
    __shared__ u16 Ks[2][64 * 64];
    __shared__ u16 Vs[2][64 * 64];

    const int tid  = threadIdx.x;
    const int lane = tid & 63;
    const int w    = tid >> 6;     // wave 0..3
    const int qi   = lane & 31;
    const int hi   = lane >> 5;

    const int bid  = blockIdx.x;
    const int j    = bid & 255;
    const int half = bid >> 8;
    const int bh   = j & 31;
    const int s    = j >> 5;
    const int c    = half ? (15 - s) : s;   // 128-row chunk index, 0..15

    const size_t qkb  = (size_t)bh * GL * 64;
    const size_t vtbo = (size_t)bh * 64 * GL;

    const int qrow = c * 128 + w * 32 + qi;
    bf16x8 qf[4];
#pragma unroll
    for (int dc = 0; dc < 4; ++dc)
        qf[dc] = *reinterpret_cast<const bf16x8*>(
            qg + qkb + (size_t)qrow * 64 + dc * 16 + hi * 8);

    // staging: 4 waves cover 64 rows x 8 chunks; 2 gl_lds (K) + 2 (V) per lane
    const int lrow = lane >> 3;    // 0..7
    const int lch  = lane & 7;

    auto stage = [&](int t, u16* kd, u16* vd) {
#pragma unroll
        for (int cc = 0; cc < 2; ++cc) {
            const int row = cc * 32 + w * 8 + lrow;      // tile row 0..63
            const int gc  = lch ^ (row & 7);             // pre-swizzled chunk
            const int ksrc = t * 64 + (row & 32) + sig5(row & 31);
            gl_lds16(kg + qkb + (size_t)ksrc * 64 + gc * 8,
                     kd + (cc * 32 + w * 8) * 64);
            gl_lds16(vtg + vtbo + (size_t)row * GL + t * 64 + gc * 8,
                     vd + (cc * 32 + w * 8) * 64);
        }
    };

    float m_run = -__builtin_inff(), l_run = 0.f;
    f32x16 o0 = {0.f,0.f,0.f,0.f,0.f,0.f,0.f,0.f,0.f,0.f,0.f,0.f,0.f,0.f,0.f,0.f};
    f32x16 o1 = o0;

    stage(0, Ks[0], Vs[0]);
    __syncthreads();

    // unmasked pairs: tiles 0..2c-1 (compile-time buffer indices)
    for (int tt = 0; tt < c; ++tt) {
        stage(2 * tt + 1, Ks[1], Vs[1]);
        attn_step32<false>(Ks[0], Vs[0], qf, qrow, (2 * tt) * 64, qi, hi,
                           m_run, l_run, o0, o1);
        __syncthreads();
        stage(2 * tt + 2, Ks[0], Vs[0]);
        attn_step32<false>(Ks[1], Vs[1], qf, qrow, (2 * tt + 1) * 64, qi, hi,
                           m_run, l_run, o0, o1);
        __syncthreads();
    }
    // tile 2c (buf0): diagonal for waves 0-1, fully unmasked for waves 2-3
    stage(2 * c + 1, Ks[1], Vs[1]);
    if (w < 2)
        attn_step32<true>(Ks[0], Vs[0], qf, qrow, (2 * c) * 64, qi, hi,
                          m_run, l_run, o0, o1);
    else
        attn_step32<false>(Ks[0], Vs[0], qf, qrow, (2 * c) * 64, qi, hi,
                           m_run, l_run, o0, o1);
    __syncthreads();
    // tile 2c+1 (buf1): diagonal for waves 2-3; waves 0-1 fully masked -> skip
    if (w >= 2)
        attn_step32<true>(Ks[1], Vs[1], qf, qrow, (2 * c + 1) * 64, qi, hi,
                          m_run, l_run, o0, o1);

    // ---- epilogue: O[q][hd], hd = (r&3) + 8*(r>>2) + 4*hi (+32 for o1) ----
    const int b = bh >> 4, h = bh & 15;
    const float inv = 1.f / l_run;
    u16* obase = og + ((size_t)(b * GL + qrow)) * 1024 + h * 64 + 4 * hi;
#pragma unroll
    for (int rq = 0; rq < 4; ++rq) {
        ushort4 w0, w1;
        w0.x = bfu(o0[4 * rq] * inv);     w0.y = bfu(o0[4 * rq + 1] * inv);
        w0.z = bfu(o0[4 * rq + 2] * inv); w0.w = bfu(o0[4 * rq + 3] * inv);
        *reinterpret_cast<ushort4*>(obase + 8 * rq) = w0;
        w1.x = bfu(o1[4 * rq] * inv);     w1.y = bfu(o1[4 * rq + 1] * inv);
        w1.z = bfu(o1[4 * rq + 2] * inv); w1.w = bfu(o1[4 * rq + 3] * inv);
        *reinterpret_cast<ushort4*>(obase + 32 + 8 * rq) = w1;
    }
}

// ---------------------------------------------------------------------------
extern "C" void kernel_launch(void* const* d_in, const int* in_sizes, int n_in,
                              void* d_out, int out_size, void* d_ws, size_t ws_size,
                              hipStream_t stream) {
    const float* emb = (const float*)d_in[0];
    const float* Wq  = (const float*)d_in[1];
    const float* Wk  = (const float*)d_in[2];
    const float* Wv  = (const float*)d_in[3];
    const float* Wo  = (const float*)d_in[4];
    float* out = (float*)d_out;

    char* ws = (char*)d_ws;
    u16* qb   = (u16*)(ws);
    u16* kb   = (u16*)(ws + ( 8u << 20));
    u16* vtb  = (u16*)(ws + (16u << 20));
    u16* ab   = (u16*)(ws + (24u << 20));
    u16* embb = (u16*)(ws + (32u << 20));
    u16* wqt  = (u16*)(ws + (40u << 20));
    u16* wot  = (u16*)(ws + (46u << 20));

    dim3 blk(256);

    cast_bf16<<<dim3(2048), blk, 0, stream>>>(emb, embb, GM * GK / 8);
    transpose_qkv<<<dim3(16, 1, 48), blk, 0, stream>>>(Wq, Wk, Wv, wqt);
    transpose_bf16<<<dim3(16, 16, 1), blk, 0, stream>>>(Wo, wot, 1024, 1024);

    // fused Q/K/V projections (one dispatch, 48 n-slices)
    gemm_mfma<<<dim3(GM / 128, 48), blk, 0, stream>>>(
        embb, wqt, nullptr, qb, kb, vtb, 1);

    // attention: 512 blocks x 4 waves, 128-row chunks, complementary pairing
    attn_mfma<<<dim3(512), blk, 0, stream>>>(qb, kb, vtb, ab);

    // output projection
    gemm_mfma<<<dim3(GM / 128, 16), blk, 0, stream>>>(
        ab, wot, out, nullptr, nullptr, nullptr, 0);
}

// Round 9
// 109.078 us; speedup vs baseline: 1.5709x; 1.0074x over previous
//
#include <hip/hip_runtime.h>
#include <hip/hip_bf16.h>

// B=2, L=2048, D=1024, H=16, HD=64.  M = B*L = 4096, K = D = 1024.
// ws (bytes):
//   qb   @ 0MB   bf16 [32][2048][64]   (Q pre-scaled by SM_SCALE)
//   kb   @ 8MB   bf16 [32][2048][64]
//   vtb  @16MB   bf16 [32][64][2048]   (V transposed)
//   ab   @24MB   bf16 [4096][1024]     (attn concat out)
//   embb @32MB   bf16 [4096][1024]
//   wqt  @40MB   bf16 [48][64][1024]   (wqt/wkt/wvt contiguous, 2MB each)
//   wot  @46MB   bf16 [1024][1024]     (Wo transposed)

#define GM 4096
#define GK 1024
#define GL 2048
#define GH 16

typedef __attribute__((ext_vector_type(8))) short bf16x8;
typedef __attribute__((ext_vector_type(4))) float f32x4;
typedef __attribute__((ext_vector_type(16))) float f32x16;
typedef unsigned short u16;

__device__ __forceinline__ u16 bfu(float x) {
    __hip_bfloat16 h = __float2bfloat16(x);
    return *reinterpret_cast<u16*>(&h);
}
__device__ __forceinline__ unsigned pack_bf16(float a, float b) {
    return ((unsigned)bfu(b) << 16) | bfu(a);
}
// truncation-pack two f32 -> {bf16(a) lo, bf16(b) hi} in one v_perm_b32
__device__ __forceinline__ unsigned pack_trunc(float a, float b) {
    return __builtin_amdgcn_perm(__float_as_uint(b), __float_as_uint(a), 0x07060302u);
}
__device__ __forceinline__ void gl_lds16(const void* g, void* l) {
    __builtin_amdgcn_global_load_lds(
        (__attribute__((address_space(1))) void*)(g),
        (__attribute__((address_space(3))) void*)(l),
        16, 0, 0);
}
__device__ __forceinline__ float fexp2(float x) {
#if __has_builtin(__builtin_amdgcn_exp2f)
    return __builtin_amdgcn_exp2f(x);
#else
    return __expf(x * 0.6931471805599453f);
#endif
}
// k-row staging permutation: tile row c holds global k-row sig5(c) (within 32).
// Makes QK^T C-regs land exactly in PV B-fragment order (own-lane, no P LDS).
__device__ __forceinline__ int sig5(int c) {
    return (c & 3) | (((c >> 3) & 1) << 2) | (((c >> 2) & 1) << 3) | (c & 16);
}

// 0.125 (1/sqrt(64)) folded with log2(e): softmax done in exp2 domain.
#define SM_SCALE 0.1803368801111204f
// defer-max threshold (exp2 domain): P bounded by 2^8.
#define RESCALE_THR 8.0f

// ---------------------------------------------------------------------------
// fp32 -> bf16 cast, 8 elements/thread.
// ---------------------------------------------------------------------------
__global__ __launch_bounds__(256) void cast_bf16(
    const float* __restrict__ src, u16* __restrict__ dst, int n8)
{
    int i = blockIdx.x * 256 + threadIdx.x;
    if (i >= n8) return;
    float4 v0 = reinterpret_cast<const float4*>(src)[i * 2];
    float4 v1 = reinterpret_cast<const float4*>(src)[i * 2 + 1];
    uint4 o;
    o.x = pack_bf16(v0.x, v0.y);
    o.y = pack_bf16(v0.z, v0.w);
    o.z = pack_bf16(v1.x, v1.y);
    o.w = pack_bf16(v1.z, v1.w);
    reinterpret_cast<uint4*>(dst)[i] = o;
}

// ---------------------------------------------------------------------------
// Fused Wq/Wk/Wv transpose+convert: z in [0,48) -> head (z&15) of proj (z>>4).
// ---------------------------------------------------------------------------
__global__ __launch_bounds__(256) void transpose_qkv(
    const float* __restrict__ Wq, const float* __restrict__ Wk,
    const float* __restrict__ Wv, u16* __restrict__ dst)
{
    __shared__ float T[64][65];
    const int t = threadIdx.x;
    const int z = blockIdx.z;
    const int r0 = blockIdx.x * 64;
    const float* s = (z < 16 ? Wq : (z < 32 ? Wk : Wv)) + (size_t)(z & 15) * 65536;
    u16* d = dst + (size_t)z * 65536;
#pragma unroll
    for (int i = 0; i < 4; ++i) {
        int idx = i * 256 + t;
        int row = idx >> 4, col = (idx & 15) * 4;
        float4 v = *reinterpret_cast<const float4*>(&s[(size_t)(r0 + row) * 64 + col]);
        T[row][col] = v.x; T[row][col + 1] = v.y;
        T[row][col + 2] = v.z; T[row][col + 3] = v.w;
    }
    __syncthreads();
#pragma unroll
    for (int i = 0; i < 4; ++i) {
        int idx = i * 256 + t;
        int oc = idx >> 4, ok = (idx & 15) * 4;
        ushort4 o;
        o.x = bfu(T[ok][oc]);     o.y = bfu(T[ok + 1][oc]);
        o.z = bfu(T[ok + 2][oc]); o.w = bfu(T[ok + 3][oc]);
        *reinterpret_cast<ushort4*>(&d[(size_t)oc * 1024 + r0 + ok]) = o;
    }
}

// ---------------------------------------------------------------------------
// Generic transpose+convert (for Wo): src fp32 [R][C] -> dst bf16 [C][R].
// ---------------------------------------------------------------------------
__global__ __launch_bounds__(256) void transpose_bf16(
    const float* __restrict__ src, u16* __restrict__ dst, int R, int C)
{
    __shared__ float T[64][65];
    const int t = threadIdx.x;
    const int r0 = blockIdx.x * 64, c0 = blockIdx.y * 64;
#pragma unroll
    for (int i = 0; i < 4; ++i) {
        int idx = i * 256 + t;
        int row = idx >> 4, col = (idx & 15) * 4;
        float4 v = *reinterpret_cast<const float4*>(&src[(size_t)(r0 + row) * C + c0 + col]);
        T[row][col] = v.x; T[row][col + 1] = v.y;
        T[row][col + 2] = v.z; T[row][col + 3] = v.w;
    }
    __syncthreads();
#pragma unroll
    for (int i = 0; i < 4; ++i) {
        int idx = i * 256 + t;
        int oc = idx >> 4, ok = (idx & 15) * 4;
        ushort4 o;
        o.x = bfu(T[ok][oc]);     o.y = bfu(T[ok + 1][oc]);
        o.z = bfu(T[ok + 2][oc]); o.w = bfu(T[ok + 3][oc]);
        *reinterpret_cast<ushort4*>(&dst[(size_t)(c0 + oc) * R + r0 + ok]) = o;
    }
}

// ---------------------------------------------------------------------------
// bf16 MFMA GEMM (m97 structure). fused=1: by -> proj/head; Q epilogue applies
// SM_SCALE. fused=0: by = n-tile, fp32 out.
// ---------------------------------------------------------------------------
__global__ __launch_bounds__(256) void gemm_mfma(
    const u16* __restrict__ A, const u16* __restrict__ Bt,
    float* __restrict__ Cf, u16* __restrict__ Cq, u16* __restrict__ Ck,
    u16* __restrict__ Cvt, int fused)
{
    __shared__ u16 As[128 * 64];
    __shared__ u16 Bs[64 * 64];

    const int tid  = threadIdx.x;
    const int lane = tid & 63;
    const int w    = tid >> 6;
    const int g    = lane >> 4;
    const int c15  = lane & 15;
    const int wr   = w >> 1, wc = w & 1;
    const int m0   = blockIdx.x * 128;
    const int by   = blockIdx.y;

    const u16* Bb = Bt + (size_t)by * (64 * 1024);
    const int srow8  = lane >> 3;
    const int schunk = lane & 7;

    f32x4 acc[4][2];
#pragma unroll
    for (int mf = 0; mf < 4; ++mf)
#pragma unroll
        for (int nf = 0; nf < 2; ++nf) acc[mf][nf] = f32x4{0.f, 0.f, 0.f, 0.f};

    for (int k0 = 0; k0 < GK; k0 += 64) {
#pragma unroll
        for (int c = 0; c < 4; ++c) {
            int row = c * 32 + w * 8 + srow8;
            int gc = schunk ^ (row & 7);
            gl_lds16(A + (size_t)(m0 + row) * GK + k0 + gc * 8,
                     As + c * 2048 + w * 512);
        }
#pragma unroll
        for (int c = 0; c < 2; ++c) {
            int row = c * 32 + w * 8 + srow8;
            int gc = schunk ^ (row & 7);
            gl_lds16(Bb + (size_t)row * GK + k0 + gc * 8,
                     Bs + c * 2048 + w * 512);
        }
        __syncthreads();

#pragma unroll
        for (int kc = 0; kc < 2; ++kc) {
            bf16x8 a[4], b[2];
#pragma unroll
            for (int mf = 0; mf < 4; ++mf) {
                int row = wr * 64 + mf * 16 + c15;
                int ch = (kc * 4 + g) ^ (row & 7);
                a[mf] = *reinterpret_cast<const bf16x8*>(As + row * 64 + ch * 8);
            }
#pragma unroll
            for (int nf = 0; nf < 2; ++nf) {
                int row = wc * 32 + nf * 16 + c15;
                int ch = (kc * 4 + g) ^ (row & 7);
                b[nf] = *reinterpret_cast<const bf16x8*>(Bs + row * 64 + ch * 8);
            }
#pragma unroll
            for (int mf = 0; mf < 4; ++mf)
#pragma unroll
                for (int nf = 0; nf < 2; ++nf)
                    acc[mf][nf] = __builtin_amdgcn_mfma_f32_16x16x32_bf16(
                        a[mf], b[nf], acc[mf][nf], 0, 0, 0);
        }
        __syncthreads();
    }

    // ---- epilogue ----
    if (!fused) {
#pragma unroll
        for (int mf = 0; mf < 4; ++mf) {
            int m = m0 + wr * 64 + mf * 16 + g * 4;
#pragma unroll
            for (int nf = 0; nf < 2; ++nf) {
                int n = by * 64 + wc * 32 + nf * 16 + c15;
#pragma unroll
                for (int r = 0; r < 4; ++r)
                    Cf[(size_t)(m + r) * 1024 + n] = acc[mf][nf][r];
            }
        }
        return;
    }
    const int proj = by >> 4;
    const int head = by & 15;
    const int b = m0 >> 11, l0 = m0 & 2047;
    if (proj < 2) {
        u16* C = proj ? Ck : Cq;
        const float qs = proj ? 1.f : SM_SCALE;   // pre-scale Q for softmax
        const size_t bh = ((size_t)(b * GH + head)) * GL * 64;
#pragma unroll
        for (int mf = 0; mf < 4; ++mf) {
            int l = l0 + wr * 64 + mf * 16 + g * 4;
#pragma unroll
            for (int nf = 0; nf < 2; ++nf) {
                int n = wc * 32 + nf * 16 + c15;
#pragma unroll
                for (int r = 0; r < 4; ++r)
                    C[bh + (size_t)(l + r) * 64 + n] = bfu(acc[mf][nf][r] * qs);
            }
        }
    } else {
        const size_t bh = ((size_t)(b * GH + head)) * 64 * GL;
#pragma unroll
        for (int mf = 0; mf < 4; ++mf) {
            int l = l0 + wr * 64 + mf * 16 + g * 4;
#pragma unroll
            for (int nf = 0; nf < 2; ++nf) {
                int n = wc * 32 + nf * 16 + c15;
                ushort4 o;
                o.x = bfu(acc[mf][nf][0]); o.y = bfu(acc[mf][nf][1]);
                o.z = bfu(acc[mf][nf][2]); o.w = bfu(acc[mf][nf][3]);
                *reinterpret_cast<ushort4*>(&Cvt[bh + (size_t)n * GL + l]) = o;
            }
        }
    }
}

// ---------------------------------------------------------------------------
// One 64-k KV step, 32x32x16 MFMA, 32 q-rows per wave (swapped operands).
// K tile is sigma-permuted at staging so QK^T C-regs == PV B-frag order:
// P stays entirely in registers (no LDS round-trip, no cross-lane moves).
// ---------------------------------------------------------------------------
template <bool DOMASK>
__device__ __forceinline__ void attn_step32(
    const u16* __restrict__ Kt, const u16* __restrict__ Vt,
    const bf16x8* qf, int qrow, int j0, int qi, int hi,
    float& m_run, float& l_run, f32x16& o0, f32x16& o1)
{
    const int swz = qi & 7;   // rows qi and 32+qi share (row&7)

    // ---- S^T = K . Q^T : two stacked 32x32 tiles, d-contraction = 4 MFMA ----
    f32x16 s0 = {0.f,0.f,0.f,0.f,0.f,0.f,0.f,0.f,0.f,0.f,0.f,0.f,0.f,0.f,0.f,0.f};
    f32x16 s1 = s0;
#pragma unroll
    for (int dc = 0; dc < 4; ++dc) {
        const int ch = ((dc * 2 + hi) ^ swz) * 8;
        bf16x8 kf0 = *reinterpret_cast<const bf16x8*>(Kt + qi * 64 + ch);
        bf16x8 kf1 = *reinterpret_cast<const bf16x8*>(Kt + (32 + qi) * 64 + ch);
        s0 = __builtin_amdgcn_mfma_f32_32x32x16_bf16(kf0, qf[dc], s0, 0, 0, 0);
        s1 = __builtin_amdgcn_mfma_f32_32x32x16_bf16(kf1, qf[dc], s1, 0, 0, 0);
    }

    // reg r of tile kt holds S for global k = j0 + 32*kt + klocal(r,hi):
    // klocal = (r&3) + 4*((r>>2)&1) + 8*hi + 16*((r>>3)&1)   [sigma mapping]
    if (DOMASK) {
#pragma unroll
        for (int r = 0; r < 16; ++r) {
            const int kl = (r & 3) + (((r >> 2) & 1) << 2) + (hi << 3)
                         + (((r >> 3) & 1) << 4);
            if (j0 + kl > qrow)      s0[r] = -__builtin_inff();
            if (j0 + 32 + kl > qrow) s1[r] = -__builtin_inff();
        }
    }

    // ---- row max: 4 chains then combine; cross-lane only xor-32 ----
    float ma = fmaxf(s0[0], s0[1]), mb = fmaxf(s0[2], s0[3]);
    float mc = fmaxf(s1[0], s1[1]), md = fmaxf(s1[2], s1[3]);
#pragma unroll
    for (int r = 4; r < 16; r += 4) {
        ma = fmaxf(ma, fmaxf(s0[r], s0[r + 1]));
        mb = fmaxf(mb, fmaxf(s0[r + 2], s0[r + 3]));
        mc = fmaxf(mc, fmaxf(s1[r], s1[r + 1]));
        md = fmaxf(md, fmaxf(s1[r + 2], s1[r + 3]));
    }
    float mx = fmaxf(fmaxf(ma, mb), fmaxf(mc, md));
    mx = fmaxf(mx, __shfl_xor(mx, 32));

    // ---- defer-max rescale (T13) ----
    if (!__all(mx <= m_run + RESCALE_THR)) {
        const float mnew = fmaxf(m_run, mx);
        const float scl  = fexp2(m_run - mnew);   // first tile: exp2(-inf)=0
        l_run *= scl;
        o0 *= scl;
        o1 *= scl;
        m_run = mnew;
    }

    // ---- exp + pack (pair p packs regs 2p,2p+1 = consecutive k) ----
    float rsum = 0.f;
    unsigned pk0[8], pk1[8];
#pragma unroll
    for (int p = 0; p < 8; ++p) {
        float a = fexp2(s0[2 * p] - m_run), b = fexp2(s0[2 * p + 1] - m_run);
        float c = fexp2(s1[2 * p] - m_run), d = fexp2(s1[2 * p + 1] - m_run);
        rsum += (a + b) + (c + d);
        pk0[p] = pack_trunc(a, b);
        pk1[p] = pack_trunc(c, d);
    }
    rsum += __shfl_xor(rsum, 32);
    l_run += rsum;

    // ---- O^T += V^T . P^T : B-frag j = packed pairs [4*(j&1)..+3] of tile j>>1
    __builtin_amdgcn_s_setprio(1);
#pragma unroll
    for (int j2 = 0; j2 < 4; ++j2) {
        const int J4 = (j2 & 1) * 4;
        uint4 uu;
        if (j2 < 2) { uu.x = pk0[J4]; uu.y = pk0[J4 + 1]; uu.z = pk0[J4 + 2]; uu.w = pk0[J4 + 3]; }
        else        { uu.x = pk1[J4]; uu.y = pk1[J4 + 1]; uu.z = pk1[J4 + 2]; uu.w = pk1[J4 + 3]; }
        bf16x8 pf = __builtin_bit_cast(bf16x8, uu);
        const int chv = ((j2 * 2 + hi) ^ swz) * 8;
        bf16x8 vf0 = *reinterpret_cast<const bf16x8*>(Vt + qi * 64 + chv);
        bf16x8 vf1 = *reinterpret_cast<const bf16x8*>(Vt + (32 + qi) * 64 + chv);
        o0 = __builtin_amdgcn_mfma_f32_32x32x16_bf16(vf0, pf, o0, 0, 0, 0);
        o1 = __builtin_amdgcn_mfma_f32_32x32x16_bf16(vf1, pf, o1, 0, 0, 0);
    }
    __builtin_amdgcn_s_setprio(0);
}

// ---------------------------------------------------------------------------
// Causal flash attention, uniform-work decomposition.
// 512 blocks x 256 threads. Block = (bh, pair p, row-half h):
//   slot=bid&7 (XCD), idx=bid>>3; bh=slot*4+(idx>>4); rem=idx&15; p=rem>>1,
//   h=rem&1. Block processes rows [c*128+h*64, +64) of chunks c=p and c=15-p
//   serially. Waves 0-1 (group A) handle even KV tiles, waves 2-3 (group B)
//   odd tiles (parity split), each with its own double-buffered K/V in LDS.
//   Per-chunk partial softmax states merged via LDS scratch (exact fp32).
// Every block: A=17 steps, B=15..17 -> all CUs uniformly busy, drain together.
// LDS 64KB/block -> 2 blocks/CU = 8 waves/CU sustained.
// ---------------------------------------------------------------------------
__global__ __launch_bounds__(256) void attn_mfma(
    const u16* __restrict__ qg, const u16* __restrict__ kg,
    const u16* __restrict__ vtg, u16* __restrict__ og)
{
    __shared__ u16 Ksh[2][2][4096];   // [group][slot][64*64]
    __shared__ u16 Vsh[2][2][4096];

    const int tid  = threadIdx.x;
    const int lane = tid & 63;
    const int w    = tid >> 6;     // 0..3
    const int wl   = w & 1;        // wave within group
    const int g    = w >> 1;       // 0 = even tiles, 1 = odd tiles
    const int qi   = lane & 31;
    const int hi   = lane >> 5;

    const int bid  = blockIdx.x;
    const int slot = bid & 7;
    const int idx  = bid >> 3;
    const int bh   = slot * 4 + (idx >> 4);
    const int rem  = idx & 15;
    const int p    = rem >> 1;
    const int h    = rem & 1;

    const size_t qkb  = (size_t)bh * GL * 64;
    const size_t vtbo = (size_t)bh * 64 * GL;

    float* scr = (float*)&Ksh[0][0][0];   // combine scratch (17KB, overlaid)

    // group staging: 2 waves x 4 calls cover 64 rows x 8 chunks (8KB K + 8KB V)
    auto stage = [&](int t, int s) {
        u16* kd = &Ksh[g][s][0];
        u16* vd = &Vsh[g][s][0];
#pragma unroll
        for (int cc = 0; cc < 4; ++cc) {
            const int row = wl * 32 + cc * 8 + (lane >> 3);
            const int gc  = (lane & 7) ^ (row & 7);
            const int ksrc = t * 64 + (row & 32) + sig5(row & 31);
            gl_lds16(kg + qkb + (size_t)ksrc * 64 + gc * 8,
                     kd + wl * 2048 + cc * 512);
            gl_lds16(vtg + vtbo + (size_t)row * GL + t * 64 + gc * 8,
                     vd + wl * 2048 + cc * 512);
        }
    };

    const int b  = bh >> 4, hh = bh & 15;

#pragma unroll
    for (int cpick = 0; cpick < 2; ++cpick) {
        const int c = cpick ? (15 - p) : p;
        const int qrow = c * 128 + h * 64 + wl * 32 + qi;

        bf16x8 qf[4];
#pragma unroll
        for (int dc = 0; dc < 4; ++dc)
            qf[dc] = *reinterpret_cast<const bf16x8*>(
                qg + qkb + (size_t)qrow * 64 + dc * 16 + hi * 8);

        const int nA = c + 1;
        const int n  = (g == 0) ? nA : ((h == 0) ? c : c + 1);

        float m_run = -__builtin_inff(), l_run = 0.f;
        f32x16 o0 = {0.f,0.f,0.f,0.f,0.f,0.f,0.f,0.f,0.f,0.f,0.f,0.f,0.f,0.f,0.f,0.f};
        f32x16 o1 = o0;

        if (n > 0) stage(g, 0);            // group's first tile: index g
        __syncthreads();

        for (int i = 0; i < nA; ++i) {     // nB <= nA always
            if (i < n) {
                if (i + 1 < n) stage(2 * (i + 1) + g, (i + 1) & 1);
                const u16* Kt = &Ksh[g][i & 1][0];
                const u16* Vt = &Vsh[g][i & 1][0];
                const int j0 = (2 * i + g) * 64;
                if (i == c && g == h)
                    attn_step32<true>(Kt, Vt, qf, qrow, j0, qi, hi, m_run, l_run, o0, o1);
                else
                    attn_step32<false>(Kt, Vt, qf, qrow, j0, qi, hi, m_run, l_run, o0, o1);
            }
            __syncthreads();
        }

        // ---- combine partials across the parity groups (exact fp32) ----
        const int sidx = (wl * 64 + lane) * 34;
        if (g == 1) {
#pragma unroll
            for (int r = 0; r < 16; ++r) {
                scr[sidx + r]      = o0[r];
                scr[sidx + 16 + r] = o1[r];
            }
            scr[sidx + 32] = m_run;
            scr[sidx + 33] = l_run;
        }
        __syncthreads();
        if (g == 0) {
            const float mB = scr[sidx + 32], lB = scr[sidx + 33];
            const float m  = fmaxf(m_run, mB);
            const float sA = fexp2(m_run - m);
            const float sB = fexp2(mB - m);
            const float inv = 1.f / (l_run * sA + lB * sB);
            u16* obase = og + ((size_t)(b * GL + qrow)) * 1024 + hh * 64 + 4 * hi;
#pragma unroll
            for (int rq = 0; rq < 4; ++rq) {
                ushort4 w0, w1;
                w0.x = bfu((o0[4*rq]   * sA + scr[sidx + 4*rq]   * sB) * inv);
                w0.y = bfu((o0[4*rq+1] * sA + scr[sidx + 4*rq+1] * sB) * inv);
                w0.z = bfu((o0[4*rq+2] * sA + scr[sidx + 4*rq+2] * sB) * inv);
                w0.w = bfu((o0[4*rq+3] * sA + scr[sidx + 4*rq+3] * sB) * inv);
                *reinterpret_cast<ushort4*>(obase + 8 * rq) = w0;
                w1.x = bfu((o1[4*rq]   * sA + scr[sidx + 16 + 4*rq]   * sB) * inv);
                w1.y = bfu((o1[4*rq+1] * sA + scr[sidx + 16 + 4*rq+1] * sB) * inv);
                w1.z = bfu((o1[4*rq+2] * sA + scr[sidx + 16 + 4*rq+2] * sB) * inv);
                w1.w = bfu((o1[4*rq+3] * sA + scr[sidx + 16 + 4*rq+3] * sB) * inv);
                *reinterpret_cast<ushort4*>(obase + 32 + 8 * rq) = w1;
            }
        }
        __syncthreads();   // scratch + staging buffers free before next chunk
    }
}

// ---------------------------------------------------------------------------
extern "C" void kernel_launch(void* const* d_in, const int* in_sizes, int n_in,
                              void* d_out, int out_size, void* d_ws, size_t ws_size,
                              hipStream_t stream) {
    const float* emb = (const float*)d_in[0];
    const float* Wq  = (const float*)d_in[1];
    const float* Wk  = (const float*)d_in[2];
    const float* Wv  = (const float*)d_in[3];
    const float* Wo  = (const float*)d_in[4];
    float* out = (float*)d_out;

    char* ws = (char*)d_ws;
    u16* qb   = (u16*)(ws);
    u16* kb   = (u16*)(ws + ( 8u << 20));
    u16* vtb  = (u16*)(ws + (16u << 20));
    u16* ab   = (u16*)(ws + (24u << 20));
    u16* embb = (u16*)(ws + (32u << 20));
    u16* wqt  = (u16*)(ws + (40u << 20));
    u16* wot  = (u16*)(ws + (46u << 20));

    dim3 blk(256);

    cast_bf16<<<dim3(2048), blk, 0, stream>>>(emb, embb, GM * GK / 8);
    transpose_qkv<<<dim3(16, 1, 48), blk, 0, stream>>>(Wq, Wk, Wv, wqt);
    transpose_bf16<<<dim3(16, 16, 1), blk, 0, stream>>>(Wo, wot, 1024, 1024);

    // fused Q/K/V projections (one dispatch, 48 n-slices)
    gemm_mfma<<<dim3(GM / 128, 48), blk, 0, stream>>>(
        embb, wqt, nullptr, qb, kb, vtb, 1);

    // attention: 512 uniform blocks (bh, pair, row-half), parity KV-split
    attn_mfma<<<dim3(512), blk, 0, stream>>>(qb, kb, vtb, ab);

    // output projection
    gemm_mfma<<<dim3(GM / 128, 16), blk, 0, stream>>>(
        ab, wot, out, nullptr, nullptr, nullptr, 0);
}